// Round 2
// baseline (349.424 us; speedup 1.0000x reference)
//
#include <hip/hip_runtime.h>
#include <math.h>

#define N_LM 543
#define ROW 1629          // floats per row
// total floats = 32768*1629 = 53,379,072 = 4,448,256 * 12 (exact, no tail)
// one thread = 4 points = 12 floats = 3 float4 (16B-aligned: 48B chunks)

__device__ __forceinline__ void row_params(const float* __restrict__ in, unsigned t,
                                           float& c, float& st, float& inv_s,
                                           float& nx, float& ny, float& nz) {
    const float* row = in + (size_t)t * ROW;
    nx = row[0]; ny = row[1]; nz = row[2];              // neck (landmark 0)
    const float lsx = row[33], lsy = row[34], lsz = row[35];  // landmark 11
    const float rsx = row[36], rsy = row[37], rsz = row[38];  // landmark 12
    const float svx = rsx - lsx;
    const float svy = rsy - lsy;
    const float svz = rsz - lsz;
    const float s = sqrtf(svx*svx + svy*svy + svz*svz) + 1e-8f;
    inv_s = 1.0f / s;
    const float sxz_n = sqrtf(svx*svx + svz*svz) + 1e-8f;
    c = svx / sxz_n;
    c = fminf(fmaxf(c, -1.0f), 1.0f);
    st = sqrtf(fmaxf(1.0f - c*c, 0.0f));
    if (fabsf(c) > 0.9999f) { c = 1.0f; st = 0.0f; }   // R = I branch
}

__global__ __launch_bounds__(256)
void sim3_vec(const float4* __restrict__ in4, float4* __restrict__ out4,
              const float* __restrict__ in) {
    const unsigned i = blockIdx.x * 256u + threadIdx.x;   // < 4,448,256
    const size_t q = (size_t)i * 3u;

    const float4 a = in4[q + 0];
    const float4 b = in4[q + 1];
    const float4 d = in4[q + 2];
    const float f[12] = {a.x, a.y, a.z, a.w, b.x, b.y, b.z, b.w, d.x, d.y, d.z, d.w};

    const unsigned P0 = 4u * i;                // first point index
    const unsigned t0 = P0 / 543u;             // magic-mul division
    const unsigned t3 = (P0 + 3u) / 543u;

    float c0, st0, is0, nx0, ny0, nz0;
    row_params(in, t0, c0, st0, is0, nx0, ny0, nz0);
    float c1 = c0, st1 = st0, is1 = is0, nx1 = nx0, ny1 = ny0, nz1 = nz0;
    unsigned split = 4u;                       // point idx where row t3 starts
    if (t3 != t0) {                            // rare (~4/543 of threads)
        row_params(in, t3, c1, st1, is1, nx1, ny1, nz1);
        split = t3 * 543u - P0;
    }

    float o[12];
#pragma unroll
    for (int j = 0; j < 4; ++j) {
        const bool hi = (unsigned)j >= split;
        const float c  = hi ? c1  : c0;
        const float st = hi ? st1 : st0;
        const float is = hi ? is1 : is0;
        const float x = f[3*j + 0] - (hi ? nx1 : nx0);
        const float y = f[3*j + 1] - (hi ? ny1 : ny0);
        const float z = f[3*j + 2] - (hi ? nz1 : nz0);
        o[3*j + 0] = ( c  * x + st * z) * is;
        o[3*j + 1] =   y * is;
        o[3*j + 2] = (-st * x + c  * z) * is;
    }

    out4[q + 0] = make_float4(o[0], o[1], o[2],  o[3]);
    out4[q + 1] = make_float4(o[4], o[5], o[6],  o[7]);
    out4[q + 2] = make_float4(o[8], o[9], o[10], o[11]);
}

extern "C" void kernel_launch(void* const* d_in, const int* in_sizes, int n_in,
                              void* d_out, int out_size, void* d_ws, size_t ws_size,
                              hipStream_t stream) {
    const float* in = (const float*)d_in[0];
    float* out = (float*)d_out;
    const int total_threads = in_sizes[0] / 12;     // 4,448,256
    const int blocks = total_threads / 256;          // 17,376 exact
    sim3_vec<<<blocks, 256, 0, stream>>>((const float4*)in, (float4*)out, in);
}